// Round 2
// baseline (627.136 us; speedup 1.0000x reference)
//
#include <hip/hip_runtime.h>
#include <math.h>

// STDP_CA3 fused: forward (Neumann solve of (I-0.5J)x = input, fp64 acc,
// M=4 with doubled tail weight) + trace/coef updates + O(N^2) J/T update,
// all in ONE persistent kernel with a manual device-scope grid barrier.
//
// Round-1 fix: Neumann weights are {0.5, 0.25, 0.125, 0.125} — the last
// term is sum_{m>=4} 0.5^m = 0.125 (geometric tail, Perron mode lambda=1).
// Round-0 submission had 0.25 (2x too heavy) -> +0.06 on every activity ->
// act01 threshold flipped -> absmax ~1.0 on J. Structure was otherwise fine.
//
// Residency proof for the spin barrier (cannot deadlock):
//   512 blocks, 256 thr (4 waves). LDS = 2*16KB + 128B ~= 33KB -> 4 blk/CU.
//   launch_bounds(256,2) -> VGPR <= 256 -> worst case 2 blk/CU. Waves:
//   2 blk * 4 waves = 8/CU <= 32. 256 CU * 2 = 512 co-resident. Exact fit.
// Cross-block data inside the kernel (y1..y3, cv/ev) moves ONLY through
// AGENT-scope atomics (bypasses non-coherent per-XCD L2 / per-CU L1).

#define NS 4096
#define NS4 (NS / 4)
#define NT 256
#define NB 512
#define RPB 8   // rows per block (4 waves x 2 rows)

typedef float vf4 __attribute__((ext_vector_type(4)));

__device__ __forceinline__ void gridbar(unsigned long long* bar,
                                        unsigned long long target)
{
    __threadfence();      // order this thread's stores to device scope
    __syncthreads();      // drains vmcnt(0): all block stores complete
    if (threadIdx.x == 0) {
        __hip_atomic_fetch_add(bar, 1ull, __ATOMIC_ACQ_REL,
                               __HIP_MEMORY_SCOPE_AGENT);
        while (__hip_atomic_load(bar, __ATOMIC_ACQUIRE,
                                 __HIP_MEMORY_SCOPE_AGENT) < target)
            __builtin_amdgcn_s_sleep(1);
    }
    __syncthreads();
}

// Per-index state init (prior dispatch => its plain stores are coherent
// for the fused kernel). Also zeroes the barrier counter.
__global__ __launch_bounds__(256) void k_init(
    const float* __restrict__ Bneg_in, const float* __restrict__ eta_in,
    const float* __restrict__ tcnt_in,
    const int* __restrict__ prev, const int* __restrict__ curr,
    float* __restrict__ dv_v, float* __restrict__ etam_v,
    float* __restrict__ prevb_v, float* __restrict__ curf_v,
    float* __restrict__ bn_v,
    float* __restrict__ out_Bneg, float* __restrict__ out_eta,
    float* __restrict__ out_cnt,
    unsigned long long* __restrict__ bar)
{
    int i = blockIdx.x * blockDim.x + threadIdx.x;
    if (i == 0) *bar = 0ull;
    if (i >= NS) return;
    int p = prev[i];
    float pb = (p > 0) ? 1.f : 0.f;
    float ei = pb + 0.99f * eta_in[i];          // eta_invs_n
    out_eta[i] = ei;
    out_cnt[i] = 0.99f * tcnt_in[i] + pb;       // real_T_count_n
    float bn = 0.9f * Bneg_in[i];               // B_neg_n (A_NEG=0)
    out_Bneg[i] = bn;
    bn_v[i] = (bn < 0.f) ? 0.f : bn;
    prevb_v[i] = pb;
    curf_v[i] = (curr[i] > 0) ? 1.f : 0.f;
    float eta = 1.f / ei;
    bool upd = (p == 1);
    dv_v[i]   = upd ? (1.f - eta) : 1.f;
    etam_v[i] = upd ? eta : 0.f;
}

__global__ __launch_bounds__(256, 2) void k_fused(
    const float* __restrict__ Jm, const float* __restrict__ inp,
    const float* __restrict__ Bpos_in, const float* __restrict__ rTt,
    const float* __restrict__ dv_v, const float* __restrict__ etam_v,
    const float* __restrict__ prevb_v, const float* __restrict__ curf_v,
    const float* __restrict__ bn_v,
    float* __restrict__ cv_v, float* __restrict__ ev_v,
    float* __restrict__ y1, float* __restrict__ y2, float* __restrict__ y3,
    unsigned long long* __restrict__ bar,
    float* __restrict__ out_act, float* __restrict__ out_Bpos,
    float* __restrict__ outJ, float* __restrict__ outT)
{
    __shared__ float xl[NS];    // x stage for matvec; reused for cv stage
    __shared__ float evl[NS];   // ev stage
    __shared__ float rowAX[RPB], rowBN[RPB], rowPB[RPB], rowDC[RPB];

    const int t = threadIdx.x;
    const int w = t >> 6;
    const int lane = t & 63;
    const int r0 = blockIdx.x * RPB + w * 2;    // this wave's 2 rows

    // fp64 activity accumulator lives in lane0 registers across passes
    double acc0 = (double)inp[r0];
    double acc1 = (double)inp[r0 + 1];

    const float4* J0 = (const float4*)(Jm + (size_t)r0 * NS);
    const float4* J1 = (const float4*)(Jm + (size_t)(r0 + 1) * NS);

    float* const ybuf[3] = {y1, y2, y3};
    // weights on x1..x4: 0.5^m, last = geometric tail sum_{m>=4} 0.5^m = 0.125
    const double wgt[4] = {0.5, 0.25, 0.125, 0.125};

    // dot of both rows against xs[0..1023] float4s (inlined per addr space)
    auto dot2 = [&](auto xs, double& s0, double& s1) {
#pragma unroll
        for (int q = 0; q < 16; ++q) {
            float4 xv = xs[lane + 64 * q];
            float4 a0 = J0[lane + 64 * q];
            float4 a1 = J1[lane + 64 * q];
            s0 += (double)a0.x * xv.x + (double)a0.y * xv.y +
                  (double)a0.z * xv.z + (double)a0.w * xv.w;
            s1 += (double)a1.x * xv.x + (double)a1.y * xv.y +
                  (double)a1.z * xv.z + (double)a1.w * xv.w;
        }
    };

#pragma unroll
    for (int m = 0; m < 4; ++m) {
        double s0 = 0.0, s1 = 0.0;
        if (m == 0) {
            dot2((const float4*)inp, s0, s1);
        } else {
            // stage y_{m} into LDS with coherent (agent) loads: written by
            // other blocks this kernel -> must bypass stale L1/L2.
            const float* ys = ybuf[m - 1];
            for (int idx = t; idx < NS; idx += NT)
                xl[idx] = __hip_atomic_load(ys + idx, __ATOMIC_RELAXED,
                                            __HIP_MEMORY_SCOPE_AGENT);
            __syncthreads();
            dot2((const float4*)xl, s0, s1);
        }
#pragma unroll
        for (int off = 32; off; off >>= 1) {
            s0 += __shfl_down(s0, off, 64);
            s1 += __shfl_down(s1, off, 64);
        }
        if (lane == 0) {
            acc0 += wgt[m] * s0;
            acc1 += wgt[m] * s1;
            if (m < 3) {
                float* yd = ybuf[m];
                __hip_atomic_store(yd + r0, (float)s0, __ATOMIC_RELAXED,
                                   __HIP_MEMORY_SCOPE_AGENT);
                __hip_atomic_store(yd + r0 + 1, (float)s1, __ATOMIC_RELAXED,
                                   __HIP_MEMORY_SCOPE_AGENT);
            }
        }
        if (m < 3) gridbar(bar, (unsigned long long)(m + 1) * NB);
    }

    // ---- coefficient phase: block owns rows r0.. => owns columns r0.. ----
    if (lane == 0) {
#pragma unroll
        for (int k = 0; k < 2; ++k) {
            int r = r0 + k;
            float act = (float)(k ? acc1 : acc0);
            out_act[r] = act;
            float X = fminf(fmaxf(act, 0.f), 1.f);
            float a01 = (X >= 0.99f) ? 1.f : 0.f;
            const float lr_p = 0.1f / 0.12f;
            float Bp = fminf((1.f - lr_p) * Bpos_in[r] + lr_p * 7.f * a01, 6.f);
            out_Bpos[r] = Bp;
            float aX = (X < 0.99f) ? 0.f : X;
            float em = etam_v[r];               // masked eta (k_init)
            __hip_atomic_store(cv_v + r, em * 1.008f * Bp, __ATOMIC_RELAXED,
                               __HIP_MEMORY_SCOPE_AGENT);
            __hip_atomic_store(ev_v + r, em * 1.008f * aX, __ATOMIC_RELAXED,
                               __HIP_MEMORY_SCOPE_AGENT);
            int lr = w * 2 + k;                 // row-side locals
            rowAX[lr] = aX;
            rowBN[lr] = bn_v[r];
            rowPB[lr] = prevb_v[r];
            rowDC[lr] = em * 0.165f * aX * Bp;  // diagonal term
        }
    }
    gridbar(bar, 4ull * NB);

    // ---- update phase: stage column coef vectors (intra-kernel data) ----
    for (int idx = t; idx < NS; idx += NT) {
        xl[idx]  = __hip_atomic_load(cv_v + idx, __ATOMIC_RELAXED,
                                     __HIP_MEMORY_SCOPE_AGENT);
        evl[idx] = __hip_atomic_load(ev_v + idx, __ATOMIC_RELAXED,
                                     __HIP_MEMORY_SCOPE_AGENT);
    }
    __syncthreads();

    const vf4* dv4 = (const vf4*)dv_v;      // written by k_init: coherent
    const vf4* cu4 = (const vf4*)curf_v;
#pragma unroll
    for (int k = 0; k < 2; ++k) {
        int r = r0 + k;
        int lr = w * 2 + k;
        float aX = rowAX[lr], bn = rowBN[lr], pb = rowPB[lr], dc = rowDC[lr];
        const vf4* Jr = (const vf4*)(Jm + (size_t)r * NS);   // L3-hot
        const vf4* Tr = (const vf4*)(rTt + (size_t)r * NS);
        vf4* Jo = (vf4*)(outJ + (size_t)r * NS);
        vf4* To = (vf4*)(outT + (size_t)r * NS);
#pragma unroll 4
        for (int q = 0; q < 16; ++q) {
            int c4 = lane + 64 * q;
            vf4 Jv = Jr[c4];
            vf4 Tv = __builtin_nontemporal_load(Tr + c4);
            vf4 dv = dv4[c4];
            vf4 cu = cu4[c4];
            vf4 cv = *(const vf4*)&xl[4 * c4];
            vf4 ev = *(const vf4*)&evl[4 * c4];
            vf4 jo, to;
#pragma unroll
            for (int c = 0; c < 4; ++c) {
                jo[c] = fminf(fmaxf(dv[c] * Jv[c] + cv[c] * aX + ev[c] * bn,
                                    0.f), 1.f);
                to[c] = 0.99f * Tv[c] + pb * cu[c];
            }
            unsigned di = (unsigned)(r - 4 * c4);   // diagonal element
            if (di < 4u)
                jo[di] = fminf(fmaxf(dv[di] * Jv[di] + dc, 0.f), 1.f);
            __builtin_nontemporal_store(jo, Jo + c4);
            __builtin_nontemporal_store(to, To + c4);
        }
    }
}

extern "C" void kernel_launch(void* const* d_in, const int* in_sizes, int n_in,
                              void* d_out, int out_size, void* d_ws, size_t ws_size,
                              hipStream_t stream)
{
    const float* inp   = (const float*)d_in[0];
    const float* Jm    = (const float*)d_in[1];
    const float* Bpos  = (const float*)d_in[2];
    const float* Bneg  = (const float*)d_in[3];
    const float* etaiv = (const float*)d_in[4];
    const float* rTt   = (const float*)d_in[5];
    const float* tcnt  = (const float*)d_in[6];
    const int*   prev  = (const int*)d_in[7];
    const int*   curr  = (const int*)d_in[8];

    float* out = (float*)d_out;
    const size_t NN = (size_t)NS * NS;
    float* out_act  = out;
    float* out_J    = out + NS;
    float* out_Bpos = out + NS + NN;
    float* out_Bneg = out + 2 * NS + NN;
    float* out_eta  = out + 3 * NS + NN;
    float* out_T    = out + 4 * NS + NN;
    float* out_cnt  = out + 4 * NS + 2 * NN;

    char* w = (char*)d_ws;                       // ~165 KB used
    unsigned long long* bar = (unsigned long long*)w;
    float* dv_v    = (float*)(w + 1024);
    float* etam_v  = (float*)(w + 1024 + 1 * 16384);
    float* prevb_v = (float*)(w + 1024 + 2 * 16384);
    float* curf_v  = (float*)(w + 1024 + 3 * 16384);
    float* bn_v    = (float*)(w + 1024 + 4 * 16384);
    float* cv_v    = (float*)(w + 1024 + 5 * 16384);
    float* ev_v    = (float*)(w + 1024 + 6 * 16384);
    float* y1      = (float*)(w + 1024 + 7 * 16384);
    float* y2      = (float*)(w + 1024 + 8 * 16384);
    float* y3      = (float*)(w + 1024 + 9 * 16384);

    k_init<<<NS / 256, 256, 0, stream>>>(Bneg, etaiv, tcnt, prev, curr,
        dv_v, etam_v, prevb_v, curf_v, bn_v, out_Bneg, out_eta, out_cnt, bar);

    k_fused<<<NB, NT, 0, stream>>>(Jm, inp, Bpos, rTt,
        dv_v, etam_v, prevb_v, curf_v, bn_v, cv_v, ev_v, y1, y2, y3, bar,
        out_act, out_Bpos, out_J, out_T);
}

// Round 3
// 384.735 us; speedup vs baseline: 1.6300x; 1.6300x over previous
//
#include <hip/hip_runtime.h>
#include <math.h>

// STDP_CA3 fused: forward (Neumann solve of (I-0.5J)x = input, fp64 acc,
// M=4 with geometric-tail weights {0.5,0.25,0.125,0.125}) + trace/coef
// updates + O(N^2) J/T update, ONE persistent kernel, manual grid barrier.
//
// Round-3 fix: the round-2 barrier was fence-toxic (450us, VALUBusy 2%):
//   - __threadfence() per wave per barrier -> buffer_wbl2 (L2 writeback)
//     x 2048 waves x 4 barriers;
//   - ACQUIRE agent-scope poll -> L1+L2 invalidate EVERY spin iteration,
//     512 pollers continuously wiping the per-XCD L2s that active blocks
//     are streaming J through (convoy).
// Neither is needed: all cross-block traffic (y1..3, cv/ev) uses
// AGENT-scope (sc1, L2-bypass) atomics -> MALL is the coherence point.
// Ordering: publisher stores drain at __syncthreads (emits s_waitcnt
// vmcnt(0) before s_barrier); consumer loads sit after the exit
// __syncthreads (compiler barrier, no HW speculation). So the barrier is
// now: relaxed RMW + relaxed spin + s_sleep backoff. No cache ops.
//
// Residency proof for the spin barrier (cannot deadlock):
//   512 blocks, 256 thr (4 waves). LDS = 2*16KB + 128B ~= 33KB -> 4 blk/CU.
//   launch_bounds(256,2) -> VGPR <= 256 -> worst case 2 blk/CU. Waves:
//   2 blk * 4 waves = 8/CU <= 32. 256 CU * 2 = 512 co-resident. Exact fit.

#define NS 4096
#define NS4 (NS / 4)
#define NT 256
#define NB 512
#define RPB 8   // rows per block (4 waves x 2 rows)

typedef float vf4 __attribute__((ext_vector_type(4)));

__device__ __forceinline__ void gridbar(unsigned long long* bar,
                                        unsigned long long target)
{
    // All waves' outstanding (sc1) stores drain at this barrier's
    // s_waitcnt vmcnt(0); thread 0's RMW follows in program order.
    __syncthreads();
    if (threadIdx.x == 0) {
        __hip_atomic_fetch_add(bar, 1ull, __ATOMIC_RELAXED,
                               __HIP_MEMORY_SCOPE_AGENT);
        while (__hip_atomic_load(bar, __ATOMIC_RELAXED,
                                 __HIP_MEMORY_SCOPE_AGENT) < target)
            __builtin_amdgcn_s_sleep(4);   // ~256 cy backoff, no cache ops
    }
    __syncthreads();
}

// Per-index state init (prior dispatch => its plain stores are coherent
// for the fused kernel). Also zeroes the barrier counter.
__global__ __launch_bounds__(256) void k_init(
    const float* __restrict__ Bneg_in, const float* __restrict__ eta_in,
    const float* __restrict__ tcnt_in,
    const int* __restrict__ prev, const int* __restrict__ curr,
    float* __restrict__ dv_v, float* __restrict__ etam_v,
    float* __restrict__ prevb_v, float* __restrict__ curf_v,
    float* __restrict__ bn_v,
    float* __restrict__ out_Bneg, float* __restrict__ out_eta,
    float* __restrict__ out_cnt,
    unsigned long long* __restrict__ bar)
{
    int i = blockIdx.x * blockDim.x + threadIdx.x;
    if (i == 0) *bar = 0ull;
    if (i >= NS) return;
    int p = prev[i];
    float pb = (p > 0) ? 1.f : 0.f;
    float ei = pb + 0.99f * eta_in[i];          // eta_invs_n
    out_eta[i] = ei;
    out_cnt[i] = 0.99f * tcnt_in[i] + pb;       // real_T_count_n
    float bn = 0.9f * Bneg_in[i];               // B_neg_n (A_NEG=0)
    out_Bneg[i] = bn;
    bn_v[i] = (bn < 0.f) ? 0.f : bn;
    prevb_v[i] = pb;
    curf_v[i] = (curr[i] > 0) ? 1.f : 0.f;
    float eta = 1.f / ei;
    bool upd = (p == 1);
    dv_v[i]   = upd ? (1.f - eta) : 1.f;
    etam_v[i] = upd ? eta : 0.f;
}

__global__ __launch_bounds__(256, 2) void k_fused(
    const float* __restrict__ Jm, const float* __restrict__ inp,
    const float* __restrict__ Bpos_in, const float* __restrict__ rTt,
    const float* __restrict__ dv_v, const float* __restrict__ etam_v,
    const float* __restrict__ prevb_v, const float* __restrict__ curf_v,
    const float* __restrict__ bn_v,
    float* __restrict__ cv_v, float* __restrict__ ev_v,
    float* __restrict__ y1, float* __restrict__ y2, float* __restrict__ y3,
    unsigned long long* __restrict__ bar,
    float* __restrict__ out_act, float* __restrict__ out_Bpos,
    float* __restrict__ outJ, float* __restrict__ outT)
{
    __shared__ float xl[NS];    // x stage for matvec; reused for cv stage
    __shared__ float evl[NS];   // ev stage
    __shared__ float rowAX[RPB], rowBN[RPB], rowPB[RPB], rowDC[RPB];

    const int t = threadIdx.x;
    const int w = t >> 6;
    const int lane = t & 63;
    const int r0 = blockIdx.x * RPB + w * 2;    // this wave's 2 rows

    // fp64 activity accumulator lives in lane0 registers across passes
    double acc0 = (double)inp[r0];
    double acc1 = (double)inp[r0 + 1];

    const float4* J0 = (const float4*)(Jm + (size_t)r0 * NS);
    const float4* J1 = (const float4*)(Jm + (size_t)(r0 + 1) * NS);

    float* const ybuf[3] = {y1, y2, y3};
    // weights on x1..x4: 0.5^m, last = geometric tail sum_{m>=4} 0.5^m = 0.125
    const double wgt[4] = {0.5, 0.25, 0.125, 0.125};

    // dot of both rows against xs[0..1023] float4s (inlined per addr space)
    auto dot2 = [&](auto xs, double& s0, double& s1) {
#pragma unroll
        for (int q = 0; q < 16; ++q) {
            float4 xv = xs[lane + 64 * q];
            float4 a0 = J0[lane + 64 * q];
            float4 a1 = J1[lane + 64 * q];
            s0 += (double)a0.x * xv.x + (double)a0.y * xv.y +
                  (double)a0.z * xv.z + (double)a0.w * xv.w;
            s1 += (double)a1.x * xv.x + (double)a1.y * xv.y +
                  (double)a1.z * xv.z + (double)a1.w * xv.w;
        }
    };

#pragma unroll
    for (int m = 0; m < 4; ++m) {
        double s0 = 0.0, s1 = 0.0;
        if (m == 0) {
            dot2((const float4*)inp, s0, s1);
        } else {
            // stage y_{m} into LDS with coherent (agent) loads: written by
            // other blocks this kernel -> must bypass stale L1/L2.
            const float* ys = ybuf[m - 1];
            for (int idx = t; idx < NS; idx += NT)
                xl[idx] = __hip_atomic_load(ys + idx, __ATOMIC_RELAXED,
                                            __HIP_MEMORY_SCOPE_AGENT);
            __syncthreads();
            dot2((const float4*)xl, s0, s1);
        }
#pragma unroll
        for (int off = 32; off; off >>= 1) {
            s0 += __shfl_down(s0, off, 64);
            s1 += __shfl_down(s1, off, 64);
        }
        if (lane == 0) {
            acc0 += wgt[m] * s0;
            acc1 += wgt[m] * s1;
            if (m < 3) {
                float* yd = ybuf[m];
                __hip_atomic_store(yd + r0, (float)s0, __ATOMIC_RELAXED,
                                   __HIP_MEMORY_SCOPE_AGENT);
                __hip_atomic_store(yd + r0 + 1, (float)s1, __ATOMIC_RELAXED,
                                   __HIP_MEMORY_SCOPE_AGENT);
            }
        }
        if (m < 3) gridbar(bar, (unsigned long long)(m + 1) * NB);
    }

    // ---- coefficient phase: block owns rows r0.. => owns columns r0.. ----
    if (lane == 0) {
#pragma unroll
        for (int k = 0; k < 2; ++k) {
            int r = r0 + k;
            float act = (float)(k ? acc1 : acc0);
            out_act[r] = act;
            float X = fminf(fmaxf(act, 0.f), 1.f);
            float a01 = (X >= 0.99f) ? 1.f : 0.f;
            const float lr_p = 0.1f / 0.12f;
            float Bp = fminf((1.f - lr_p) * Bpos_in[r] + lr_p * 7.f * a01, 6.f);
            out_Bpos[r] = Bp;
            float aX = (X < 0.99f) ? 0.f : X;
            float em = etam_v[r];               // masked eta (k_init)
            __hip_atomic_store(cv_v + r, em * 1.008f * Bp, __ATOMIC_RELAXED,
                               __HIP_MEMORY_SCOPE_AGENT);
            __hip_atomic_store(ev_v + r, em * 1.008f * aX, __ATOMIC_RELAXED,
                               __HIP_MEMORY_SCOPE_AGENT);
            int lr = w * 2 + k;                 // row-side locals
            rowAX[lr] = aX;
            rowBN[lr] = bn_v[r];
            rowPB[lr] = prevb_v[r];
            rowDC[lr] = em * 0.165f * aX * Bp;  // diagonal term
        }
    }
    gridbar(bar, 4ull * NB);

    // ---- update phase: stage column coef vectors (intra-kernel data) ----
    for (int idx = t; idx < NS; idx += NT) {
        xl[idx]  = __hip_atomic_load(cv_v + idx, __ATOMIC_RELAXED,
                                     __HIP_MEMORY_SCOPE_AGENT);
        evl[idx] = __hip_atomic_load(ev_v + idx, __ATOMIC_RELAXED,
                                     __HIP_MEMORY_SCOPE_AGENT);
    }
    __syncthreads();

    const vf4* dv4 = (const vf4*)dv_v;      // written by k_init: coherent
    const vf4* cu4 = (const vf4*)curf_v;
#pragma unroll
    for (int k = 0; k < 2; ++k) {
        int r = r0 + k;
        int lr = w * 2 + k;
        float aX = rowAX[lr], bn = rowBN[lr], pb = rowPB[lr], dc = rowDC[lr];
        const vf4* Jr = (const vf4*)(Jm + (size_t)r * NS);   // L2/L3-hot
        const vf4* Tr = (const vf4*)(rTt + (size_t)r * NS);
        vf4* Jo = (vf4*)(outJ + (size_t)r * NS);
        vf4* To = (vf4*)(outT + (size_t)r * NS);
#pragma unroll 4
        for (int q = 0; q < 16; ++q) {
            int c4 = lane + 64 * q;
            vf4 Jv = Jr[c4];
            vf4 Tv = __builtin_nontemporal_load(Tr + c4);
            vf4 dv = dv4[c4];
            vf4 cu = cu4[c4];
            vf4 cv = *(const vf4*)&xl[4 * c4];
            vf4 ev = *(const vf4*)&evl[4 * c4];
            vf4 jo, to;
#pragma unroll
            for (int c = 0; c < 4; ++c) {
                jo[c] = fminf(fmaxf(dv[c] * Jv[c] + cv[c] * aX + ev[c] * bn,
                                    0.f), 1.f);
                to[c] = 0.99f * Tv[c] + pb * cu[c];
            }
            unsigned di = (unsigned)(r - 4 * c4);   // diagonal element
            if (di < 4u)
                jo[di] = fminf(fmaxf(dv[di] * Jv[di] + dc, 0.f), 1.f);
            __builtin_nontemporal_store(jo, Jo + c4);
            __builtin_nontemporal_store(to, To + c4);
        }
    }
}

extern "C" void kernel_launch(void* const* d_in, const int* in_sizes, int n_in,
                              void* d_out, int out_size, void* d_ws, size_t ws_size,
                              hipStream_t stream)
{
    const float* inp   = (const float*)d_in[0];
    const float* Jm    = (const float*)d_in[1];
    const float* Bpos  = (const float*)d_in[2];
    const float* Bneg  = (const float*)d_in[3];
    const float* etaiv = (const float*)d_in[4];
    const float* rTt   = (const float*)d_in[5];
    const float* tcnt  = (const float*)d_in[6];
    const int*   prev  = (const int*)d_in[7];
    const int*   curr  = (const int*)d_in[8];

    float* out = (float*)d_out;
    const size_t NN = (size_t)NS * NS;
    float* out_act  = out;
    float* out_J    = out + NS;
    float* out_Bpos = out + NS + NN;
    float* out_Bneg = out + 2 * NS + NN;
    float* out_eta  = out + 3 * NS + NN;
    float* out_T    = out + 4 * NS + NN;
    float* out_cnt  = out + 4 * NS + 2 * NN;

    char* w = (char*)d_ws;                       // ~165 KB used
    unsigned long long* bar = (unsigned long long*)w;
    float* dv_v    = (float*)(w + 1024);
    float* etam_v  = (float*)(w + 1024 + 1 * 16384);
    float* prevb_v = (float*)(w + 1024 + 2 * 16384);
    float* curf_v  = (float*)(w + 1024 + 3 * 16384);
    float* bn_v    = (float*)(w + 1024 + 4 * 16384);
    float* cv_v    = (float*)(w + 1024 + 5 * 16384);
    float* ev_v    = (float*)(w + 1024 + 6 * 16384);
    float* y1      = (float*)(w + 1024 + 7 * 16384);
    float* y2      = (float*)(w + 1024 + 8 * 16384);
    float* y3      = (float*)(w + 1024 + 9 * 16384);

    k_init<<<NS / 256, 256, 0, stream>>>(Bneg, etaiv, tcnt, prev, curr,
        dv_v, etam_v, prevb_v, curf_v, bn_v, out_Bneg, out_eta, out_cnt, bar);

    k_fused<<<NB, NT, 0, stream>>>(Jm, inp, Bpos, rTt,
        dv_v, etam_v, prevb_v, curf_v, bn_v, cv_v, ev_v, y1, y2, y3, bar,
        out_act, out_Bpos, out_J, out_T);
}